// Round 3
// baseline (679.914 us; speedup 1.0000x reference)
//
#include <hip/hip_runtime.h>
#include <hip/hip_bf16.h>
#include <stdint.h>

typedef __bf16 bf16x8 __attribute__((ext_vector_type(8)));
typedef float f32x4 __attribute__((ext_vector_type(4)));
typedef unsigned short u16x8 __attribute__((ext_vector_type(8)));

// float -> bf16 round-to-nearest-even (bit trick; inputs are finite here)
__device__ inline unsigned short f2bf_rne(float f) {
  unsigned int u = __float_as_uint(f);
  u += 0x7fffu + ((u >> 16) & 1u);
  return (unsigned short)(u >> 16);
}

// Fused prep: one launch does both W sampling (w = mu + eps*exp(0.5*lv))
// and X cast, 8 elems/thread, 16B stores. n8w and n8x are both multiples of
// 256 so the W/X split is block-uniform (no divergence).
__global__ __launch_bounds__(256) void prep_all(
    const float4* __restrict__ wmu, const float4* __restrict__ wlv,
    const float4* __restrict__ weps, u16x8* __restrict__ wbf,
    const float4* __restrict__ x, u16x8* __restrict__ xbf,
    int n8w, int n8x) {
  int i = blockIdx.x * 256 + threadIdx.x;
  if (i < n8w) {
    float4 m0 = wmu[2 * i], m1 = wmu[2 * i + 1];
    float4 v0 = wlv[2 * i], v1 = wlv[2 * i + 1];
    float4 e0 = weps[2 * i], e1 = weps[2 * i + 1];
    u16x8 p;
    p[0] = f2bf_rne(m0.x + e0.x * __expf(0.5f * v0.x));
    p[1] = f2bf_rne(m0.y + e0.y * __expf(0.5f * v0.y));
    p[2] = f2bf_rne(m0.z + e0.z * __expf(0.5f * v0.z));
    p[3] = f2bf_rne(m0.w + e0.w * __expf(0.5f * v0.w));
    p[4] = f2bf_rne(m1.x + e1.x * __expf(0.5f * v1.x));
    p[5] = f2bf_rne(m1.y + e1.y * __expf(0.5f * v1.y));
    p[6] = f2bf_rne(m1.z + e1.z * __expf(0.5f * v1.z));
    p[7] = f2bf_rne(m1.w + e1.w * __expf(0.5f * v1.w));
    wbf[i] = p;
  } else {
    int j = i - n8w;
    if (j < n8x) {
      float4 m0 = x[2 * j], m1 = x[2 * j + 1];
      u16x8 p;
      p[0] = f2bf_rne(m0.x); p[1] = f2bf_rne(m0.y);
      p[2] = f2bf_rne(m0.z); p[3] = f2bf_rne(m0.w);
      p[4] = f2bf_rne(m1.x); p[5] = f2bf_rne(m1.y);
      p[6] = f2bf_rne(m1.z); p[7] = f2bf_rne(m1.w);
      xbf[j] = p;
    }
  }
}

// C[M,N] = A[M,K] * B[N,K]^T + bias(N), A/B bf16 row-major (K inner), C fp32.
// 128x128 block tile, 4 waves 2x2, each wave 64x64 via 4x4 of 16x16x32 MFMA.
// LDS layout XOR-swizzled (granule c of row r -> granule c^(r&7)); verified
// conflict-free (R2: SQ_LDS_BANK_CONFLICT == 0).
// Block order: 1D grid remapped into 8x8 supertiles (A+B working set 16 MB,
// fits aggregate L2) for L2/LLC locality.
#define BM 128
#define BN 128
#define BK 64

__global__ __launch_bounds__(256) void gemm_bt_bias(
    const unsigned short* __restrict__ A,   // [M][K] bf16 bits
    const unsigned short* __restrict__ B,   // [N][K] bf16 bits
    const float* __restrict__ bmu, const float* __restrict__ blv,
    const float* __restrict__ beps,
    float* __restrict__ C, int M, int N, int K) {
  __shared__ __align__(16) unsigned short As[BM * BK];
  __shared__ __align__(16) unsigned short Bs[BN * BK];

  const int tid  = threadIdx.x;
  const int wave = tid >> 6;
  const int lane = tid & 63;
  const int wm = wave >> 1;   // 0..1  (M direction)
  const int wn = wave & 1;    // 0..1  (N direction)

  // supertile remap: 2048 blocks -> (bn, bm); 8x8 blocks per supertile
  const int bid    = blockIdx.x;
  const int st     = bid >> 6;          // 0..31
  const int within = bid & 63;
  const int bn = (st & 3) * 8 + (within & 7);    // 0..31  (N blocks)
  const int bm = (st >> 2) * 8 + (within >> 3);  // 0..63  (M blocks)

  const int rowA0 = bm * BM;
  const int rowB0 = bn * BN;

  // staging: thread t loads 16B granule; swizzled so LDS granule (tid&7) of
  // row srow holds global granule (tid&7)^(srow&7)
  const int srow = tid >> 3;                                   // 0..31
  const int scol = (((tid & 7) ^ ((tid >> 3) & 7))) * 8;       // swizzled granule*8

  f32x4 acc[4][4];
#pragma unroll
  for (int i = 0; i < 4; ++i)
#pragma unroll
    for (int j = 0; j < 4; ++j)
      acc[i][j] = (f32x4){0.f, 0.f, 0.f, 0.f};

  const int mrow = lane & 15;   // fragment row (A: m, B: n)
  const int gsel = lane >> 4;   // fragment k-granule select 0..3

  for (int k0 = 0; k0 < K; k0 += BK) {
#pragma unroll
    for (int j = 0; j < 4; ++j) {
      const int r = j * 32 + srow;
      const unsigned short* gA = A + (size_t)(rowA0 + r) * K + k0 + scol;
      const unsigned short* gB = B + (size_t)(rowB0 + r) * K + k0 + scol;
      __builtin_amdgcn_global_load_lds(
          (const __attribute__((address_space(1))) unsigned int*)gA,
          (__attribute__((address_space(3))) unsigned int*)&As[(j * 256 + wave * 64) * 8],
          16, 0, 0);
      __builtin_amdgcn_global_load_lds(
          (const __attribute__((address_space(1))) unsigned int*)gB,
          (__attribute__((address_space(3))) unsigned int*)&Bs[(j * 256 + wave * 64) * 8],
          16, 0, 0);
    }
    __syncthreads();

#pragma unroll
    for (int kk = 0; kk < BK; kk += 32) {
      bf16x8 af[4], bfv[4];
#pragma unroll
      for (int mi = 0; mi < 4; ++mi) {
        const int row = wm * 64 + mi * 16 + mrow;
        const int pg = ((kk >> 3) + gsel) ^ (mrow & 7);
        af[mi] = *(const bf16x8*)&As[row * BK + pg * 8];
      }
#pragma unroll
      for (int ni = 0; ni < 4; ++ni) {
        const int row = wn * 64 + ni * 16 + mrow;
        const int pg = ((kk >> 3) + gsel) ^ (mrow & 7);
        bfv[ni] = *(const bf16x8*)&Bs[row * BK + pg * 8];
      }
#pragma unroll
      for (int mi = 0; mi < 4; ++mi)
#pragma unroll
        for (int ni = 0; ni < 4; ++ni)
          acc[mi][ni] = __builtin_amdgcn_mfma_f32_16x16x32_bf16(
              af[mi], bfv[ni], acc[mi][ni], 0, 0, 0);
    }
    __syncthreads();
  }

  // Epilogue: C/D layout col=lane&15, row=(lane>>4)*4+reg (m89-verified).
  const int colq = lane & 15;
  const int rq4  = (lane >> 4) * 4;
#pragma unroll
  for (int ni = 0; ni < 4; ++ni) {
    const int col = rowB0 + wn * 64 + ni * 16 + colq;
    const float bias = bmu[col] + beps[col] * __expf(0.5f * blv[col]);
#pragma unroll
    for (int mi = 0; mi < 4; ++mi) {
      const int rbase = rowA0 + wm * 64 + mi * 16 + rq4;
#pragma unroll
      for (int r = 0; r < 4; ++r)
        C[(size_t)(rbase + r) * N + col] = acc[mi][ni][r] + bias;
    }
  }
}

extern "C" void kernel_launch(void* const* d_in, const int* in_sizes, int n_in,
                              void* d_out, int out_size, void* d_ws, size_t ws_size,
                              hipStream_t stream) {
  const float* x    = (const float*)d_in[0];
  const float* wmu  = (const float*)d_in[1];
  const float* wlv  = (const float*)d_in[2];
  const float* bmu  = (const float*)d_in[3];
  const float* blv  = (const float*)d_in[4];
  const float* weps = (const float*)d_in[5];
  const float* beps = (const float*)d_in[6];
  float* out = (float*)d_out;

  const int M = 8192, N = 4096, K = 4096;

  // workspace: xbf [M*K] bf16 (64 MB) then wbf [N*K] bf16 (32 MB)
  unsigned short* xbf = (unsigned short*)d_ws;
  unsigned short* wbf = xbf + (size_t)M * K;

  const int n8w = N * K / 8;   // 2,097,152 (multiple of 256)
  const int n8x = M * K / 8;   // 4,194,304 (multiple of 256)
  prep_all<<<(n8w + n8x) / 256, 256, 0, stream>>>(
      (const float4*)wmu, (const float4*)wlv, (const float4*)weps, (u16x8*)wbf,
      (const float4*)x, (u16x8*)xbf, n8w, n8x);

  gemm_bt_bias<<<2048, 256, 0, stream>>>(xbf, wbf, bmu, blv, beps, out, M, N, K);
}